// Round 8
// baseline (838.077 us; speedup 1.0000x reference)
//
#include <hip/hip_runtime.h>

constexpr float F_Y0     = 0.28209479177387814f;
constexpr float F_CUTOFF = 4.6f;

typedef short short8 __attribute__((ext_vector_type(8)));
typedef float f32x4  __attribute__((ext_vector_type(4)));

__device__ __forceinline__ float siluf(float v) { return v / (1.0f + expf(-v)); }

// gfx950 hardware packed fp32->bf16 (RNE): lo = cvt(a), hi = cvt(b)
__device__ __forceinline__ unsigned pk2(float a, float b) {
  unsigned r;
  asm("v_cvt_pk_bf16_f32 %0, %1, %2" : "=v"(r) : "v"(a), "v"(b));
  return r;
}

union FragU { uint4 u; short8 s; };

__device__ __forceinline__ void load16(const float* p, float* r) {
  const float4* p4 = (const float4*)p;
#pragma unroll
  for (int i = 0; i < 4; i++) {
    float4 t = p4[i];
    r[4*i] = t.x; r[4*i+1] = t.y; r[4*i+2] = t.z; r[4*i+3] = t.w;
  }
}
__device__ __forceinline__ void store16(float* p, const float* r) {
  float4* p4 = (float4*)p;
#pragma unroll
  for (int i = 0; i < 4; i++) p4[i] = make_float4(r[4*i], r[4*i+1], r[4*i+2], r[4*i+3]);
}
__device__ __forceinline__ void load8(const float* p, float* r) {
  const float4* p4 = (const float4*)p;
#pragma unroll
  for (int i = 0; i < 2; i++) {
    float4 t = p4[i];
    r[4*i] = t.x; r[4*i+1] = t.y; r[4*i+2] = t.z; r[4*i+3] = t.w;
  }
}
__device__ __forceinline__ void store8(float* p, const float* r) {
  float4* p4 = (float4*)p;
#pragma unroll
  for (int i = 0; i < 2; i++) p4[i] = make_float4(r[4*i], r[4*i+1], r[4*i+2], r[4*i+3]);
}

// block-level sum of one float per thread -> part[blockIdx.x]
__device__ __forceinline__ void block_reduce_store(float v, float* part) {
  __shared__ float sred[4];
  int tid = threadIdx.x;
#pragma unroll
  for (int off = 32; off > 0; off >>= 1) v += __shfl_down(v, off, 64);
  if ((tid & 63) == 0) sred[tid >> 6] = v;
  __syncthreads();
  if (tid == 0) part[blockIdx.x] = sred[0] + sred[1] + sred[2] + sred[3];
}

// ---------------- per-edge precompute ----------------
__global__ __launch_bounds__(256) void k_pre(
    const int* __restrict__ species, const int* __restrict__ src, const int* __restrict__ dst,
    const float* __restrict__ rel_pos,
    float* __restrict__ dist_, float* __restrict__ scale_,
    float* __restrict__ coul_part, int E)
{
  int e = blockIdx.x * 256 + threadIdx.x;
  float ce = 0.0f;
  if (e < E) {
    float px = rel_pos[3*(size_t)e + 0];
    float py = rel_pos[3*(size_t)e + 1];
    float pz = rel_pos[3*(size_t)e + 2];
    float dist = sqrtf(px*px + py*py + pz*pz);
    float xc = dist * (1.0f / F_CUTOFF);
    bool in_cut = dist < F_CUTOFF;
    float x2 = in_cut ? xc * xc : 0.0f;
    x2 = fminf(x2, 1.0f - 1e-6f);
    float sc = in_cut ? __expf(3.0f - 3.0f / (1.0f - x2)) : 0.0f;
    dist_[e] = dist;
    scale_[e] = sc;
    float Zu = (float)species[src[e]];
    float Zv = (float)species[dst[e]];
    float raw = 0.529f * Zu * Zv / (2.0f * dist);
    float au = 0.8854f * 0.529f / (__powf(Zu, 0.23f) + __powf(Zv, 0.23f));
    float xx = dist / au;
    float screen = 0.1818f   * __expf(-3.2f    * xx)
                 + 0.5099f   * __expf(-0.9423f * xx)
                 + 0.2802f   * __expf(-0.4028f * xx)
                 + 0.02817f  * __expf(-0.2016f * xx);
    ce = raw * screen * sc;
  }
  block_reduce_store(ce, coul_part);
}

// ---------------- CSR build ----------------
__global__ __launch_bounds__(256) void k_hist(
    const int* __restrict__ dst, int* __restrict__ cnt, int E)
{
  int e = blockIdx.x * 256 + threadIdx.x;
  if (e < E) atomicAdd(&cnt[dst[e]], 1);
}

__global__ __launch_bounds__(256) void k_scan1(
    const int* __restrict__ cnt, int* __restrict__ row_ptr, int* __restrict__ bsum)
{
  __shared__ int s[256];
  int tid = threadIdx.x;
  int n = blockIdx.x * 256 + tid;
  int v = cnt[n];
  s[tid] = v;
  __syncthreads();
#pragma unroll
  for (int off = 1; off < 256; off <<= 1) {
    int t = (tid >= off) ? s[tid - off] : 0;
    __syncthreads();
    s[tid] += t;
    __syncthreads();
  }
  row_ptr[n] = s[tid] - v;
  if (tid == 255) bsum[blockIdx.x] = s[255];
}

__global__ __launch_bounds__(128) void k_scan2(int* __restrict__ bsum, int* __restrict__ boff)
{
  __shared__ int s[128];
  int tid = threadIdx.x;
  int v = bsum[tid];
  s[tid] = v;
  __syncthreads();
#pragma unroll
  for (int off = 1; off < 128; off <<= 1) {
    int t = (tid >= off) ? s[tid - off] : 0;
    __syncthreads();
    s[tid] += t;
    __syncthreads();
  }
  boff[tid] = s[tid] - v;
}

__global__ __launch_bounds__(256) void k_scan3(
    int* __restrict__ row_ptr, int* __restrict__ row_cur,
    const int* __restrict__ boff, int N, int E)
{
  int n = blockIdx.x * 256 + threadIdx.x;
  int rp = row_ptr[n] + boff[blockIdx.x];
  row_ptr[n] = rp;
  row_cur[n] = rp;
  if (n == 0) row_ptr[N] = E;
}

__global__ __launch_bounds__(256) void k_scatter(
    const int* __restrict__ src, const int* __restrict__ dst,
    const float* __restrict__ dist_, const float* __restrict__ scale_,
    int* __restrict__ row_cur,
    int* __restrict__ srcP, float* __restrict__ distP, float* __restrict__ scaleP, int E)
{
  int e = blockIdx.x * 256 + threadIdx.x;
  if (e >= E) return;
  int d = dst[e];
  int pos = atomicAdd(&row_cur[d], 1);
  srcP[pos] = src[e];
  distP[pos] = dist_[e];
  scaleP[pos] = scale_[e];
}

// ---------------- weight prepack: per layer 19 bf16 B-fragments ----------------
__global__ __launch_bounds__(256) void k_prepack(
    const float* __restrict__ kv_W3, const float* __restrict__ kv_b3,
    const float* __restrict__ fin_W3, const float* __restrict__ fin_b3,
    const float* __restrict__ kv_W2, const float* __restrict__ fin_W2,
    uint4* __restrict__ WF)
{
  int t = blockIdx.x * 256 + threadIdx.x;
  if (t >= 5 * 19 * 64) return;
  int lyr = t / (19 * 64);
  int rem = t - lyr * 19 * 64;
  int f = rem >> 6;
  int l = rem & 63;
  int qq = l >> 4;
  int o = l & 15;
  const float* W3 = (lyr < 4) ? (kv_W3 + (size_t)lyr * 32 * 256) : fin_W3;
  const float* B3 = (lyr < 4) ? (kv_b3 + (size_t)lyr * 256) : fin_b3;
  const float* W2 = (lyr < 4) ? (kv_W2 + (size_t)lyr * 32 * 32) : fin_W2;
  float v[8];
#pragma unroll
  for (int j = 0; j < 8; j++) {
    if (f < 16) {
      int kk = f * 32 + qq * 8 + j;
      int m = kk >> 4, i = kk & 15;
      v[j] = W3[m * 256 + o * 16 + i];
    } else if (f == 16) {
      int r = qq * 8 + j;
      int mp = r >> 4, i = r & 15;
      v[j] = mp ? 0.0f : B3[o * 16 + i];
    } else {
      int c = f - 17;
      int k = qq * 8 + j;
      v[j] = W2[k * 32 + c * 16 + o];
    }
  }
  uint4 dw;
  dw.x = pk2(v[0], v[1]);
  dw.y = pk2(v[2], v[3]);
  dw.z = pk2(v[4], v[5]);
  dw.w = pk2(v[6], v[7]);
  WF[t] = dw;
}

// ---------------- node init ----------------
__global__ __launch_bounds__(256) void k_node_init(
    const int* __restrict__ species, const float* __restrict__ emb,
    const float* __restrict__ Wq0,
    float* __restrict__ x, float* __restrict__ semb, float* __restrict__ q, int N)
{
  int n = blockIdx.x * 256 + threadIdx.x;
  if (n >= N) return;
  int sp = species[n] - 1;
  float xv[16];
  load16(emb + (size_t)sp * 16, xv);
  store16(x + (size_t)n * 16, xv);
  store16(semb + (size_t)n * 16, xv);
  float qv[8];
#pragma unroll
  for (int h = 0; h < 8; h++) {
    float a = 0.f;
#pragma unroll
    for (int i = 0; i < 16; i++) a += Wq0[h * 16 + i] * xv[i];
    qv[h] = a;
  }
  store8(q + (size_t)n * 8, qv);
}

// ---------------- heavy edge conv (MFMA for h2 and W3) ----------------
// Block = 64 edges, 4 waves; wave w owns the 16-edge MFMA tile [w*16, w*16+16).
// kv epilogue: scaled C-regs staged in LDS (stride 20, b128-aligned), then
// fully-contiguous float4 global stores (4 KB/block) — avoids the partial-line
// write amplification seen with direct per-lane dword stores (R7: 189 MB).
template <int MODE>
__global__ __launch_bounds__(256, 3) void k_edge_conv(
    const int* __restrict__ srcP,
    const float* __restrict__ scaleP, const float* __restrict__ distP,
    float* __restrict__ ef, const float* __restrict__ x,
    const float* __restrict__ W1, const float* __restrict__ B1,
    const float* __restrict__ B2,
    const uint4* __restrict__ WF,
    float* __restrict__ kvE, int E)
{
  __shared__ unsigned P[64 * 148];    // 37888 B; head reused as ef staging (stride 20)
  __shared__ unsigned h1P[64 * 20];   //  5120 B  bf16 h1 [edge][16 dw + pad]
  __shared__ float    h2S[64 * 36];   //  9216 B  fp32 h2 [edge][32 + pad]; tail-of-life reused as kv staging (stride 20)

  int tid = threadIdx.x;
  int w = __builtin_amdgcn_readfirstlane(tid >> 6);
  int l = tid & 63;
  int quad = l >> 4;
  int lo = l & 15;
  int q4 = quad * 4;
  int eb = blockIdx.x * 64;
  int el = eb + l;

  float xs[16];
  load16(x + (size_t)srcP[el] * 16, xs);

  // ---- h1 (wave w: m = w*8 .. w*8+7) ----
  float h1v[8];
  if (MODE == 0) {
    float dd = distP[el];
#pragma unroll
    for (int jj = 0; jj < 8; jj++) {
      int m = w * 8 + jj;
      h1v[jj] = fmaxf(B1[m] + dd * W1[15 * 32 + m], 0.f);
    }
  } else {
    float efv[16];
    if (MODE == 1) {
#pragma unroll
      for (int i = 0; i < 16; i++) efv[i] = xs[i];
      efv[15] += distP[el];
    } else {
      const float4* efp = (const float4*)(ef + (size_t)el * 16);
#pragma unroll
      for (int i = 0; i < 4; i++) {
        float4 t = efp[i];
        efv[4*i]   = t.x + xs[4*i];
        efv[4*i+1] = t.y + xs[4*i+1];
        efv[4*i+2] = t.z + xs[4*i+2];
        efv[4*i+3] = t.w + xs[4*i+3];
      }
    }
    if (MODE == 1 || MODE == 2) {
      *(float4*)&((float*)P)[l * 20 + w * 4] =
          make_float4(efv[4*w], efv[4*w+1], efv[4*w+2], efv[4*w+3]);
    }
#pragma unroll
    for (int jj = 0; jj < 8; jj++) {
      int m = w * 8 + jj;
      float a = B1[m];
#pragma unroll
      for (int i = 0; i < 16; i++) a += efv[i] * W1[i * 32 + m];
      h1v[jj] = fmaxf(a, 0.f);
    }
  }
  {
    uint4 hq;
    hq.x = pk2(h1v[0], h1v[1]);
    hq.y = pk2(h1v[2], h1v[3]);
    hq.z = pk2(h1v[4], h1v[5]);
    hq.w = pk2(h1v[6], h1v[7]);
    *(uint4*)&h1P[l * 20 + w * 4] = hq;
  }
  __syncthreads();   // S1: efS + h1P ready

  if (MODE == 1 || MODE == 2) {
    int e = tid >> 2, c = tid & 3;
    float4 v = *(const float4*)&((const float*)P)[e * 20 + c * 4];
    ((float4*)(ef + (size_t)eb * 16))[tid] = v;
  }

  // ---- h2 via MFMA ----
  {
    FragU a, b0, b1;
    a.u = *(const uint4*)&h1P[(w * 16 + lo) * 20 + q4];
    b0.u = WF[17 * 64 + l];
    b1.u = WF[18 * 64 + l];
    f32x4 hc0 = {0.f, 0.f, 0.f, 0.f};
    f32x4 hc1 = {0.f, 0.f, 0.f, 0.f};
    hc0 = __builtin_amdgcn_mfma_f32_16x16x32_bf16(a.s, b0.s, hc0, 0, 0, 0);
    hc1 = __builtin_amdgcn_mfma_f32_16x16x32_bf16(a.s, b1.s, hc1, 0, 0, 0);
    float b2a = B2[lo];
    float b2b = B2[16 + lo];
#pragma unroll
    for (int r = 0; r < 4; r++) {
      int e = quad * 4 + r;
      h2S[(w * 16 + e) * 36 + lo]      = fmaxf(hc0[r] + b2a, 0.f);
      h2S[(w * 16 + e) * 36 + 16 + lo] = fmaxf(hc1[r] + b2b, 0.f);
    }
  }
  __syncthreads();   // S2: h2S ready; efS consumed

  // ---- own-edge h2 (fp32) ----
  float h2a[32];
  {
    const float4* hp = (const float4*)&h2S[l * 36];
#pragma unroll
    for (int c = 0; c < 8; c++) {
      float4 t = hp[c];
      h2a[4*c] = t.x; h2a[4*c+1] = t.y; h2a[4*c+2] = t.z; h2a[4*c+3] = t.w;
    }
  }

  // ---- P half 0 (m = 0..15) + bias rows ----
#pragma unroll
  for (int jj = 0; jj < 4; jj++) {
    int mloc = w * 4 + jj;
    float hm = h2a[mloc];
    uint4 d0, d1;
    d0.x = pk2(hm*xs[0],  hm*xs[1]);  d0.y = pk2(hm*xs[2],  hm*xs[3]);
    d0.z = pk2(hm*xs[4],  hm*xs[5]);  d0.w = pk2(hm*xs[6],  hm*xs[7]);
    d1.x = pk2(hm*xs[8],  hm*xs[9]);  d1.y = pk2(hm*xs[10], hm*xs[11]);
    d1.z = pk2(hm*xs[12], hm*xs[13]); d1.w = pk2(hm*xs[14], hm*xs[15]);
    uint4* row = (uint4*)&P[l * 148 + mloc * 8];
    row[0] = d0; row[1] = d1;
  }
  if (w == 0) {
    uint4 d0, d1;
    d0.x = pk2(xs[0],  xs[1]);  d0.y = pk2(xs[2],  xs[3]);
    d0.z = pk2(xs[4],  xs[5]);  d0.w = pk2(xs[6],  xs[7]);
    d1.x = pk2(xs[8],  xs[9]);  d1.y = pk2(xs[10], xs[11]);
    d1.z = pk2(xs[12], xs[13]); d1.w = pk2(xs[14], xs[15]);
    uint4* row = (uint4*)&P[l * 148 + 128];
    row[0] = d0; row[1] = d1;
  }
  if (w == 1) {
    uint4 z = make_uint4(0, 0, 0, 0);
    uint4* row = (uint4*)&P[l * 148 + 136];
    row[0] = z; row[1] = z;
  }
  __syncthreads();   // S3 (h2S dead after this point)

  f32x4 acc = {0.f, 0.f, 0.f, 0.f};
  const unsigned* Arow = &P[(w * 16 + lo) * 148];
#pragma unroll
  for (int t = 0; t < 8; t++) {
    FragU a, b;
    a.u = *(const uint4*)(Arow + t * 16 + q4);
    b.u = WF[t * 64 + l];
    acc = __builtin_amdgcn_mfma_f32_16x16x32_bf16(a.s, b.s, acc, 0, 0, 0);
  }
  {
    FragU a, b;
    a.u = *(const uint4*)(Arow + 128 + q4);
    b.u = WF[16 * 64 + l];
    acc = __builtin_amdgcn_mfma_f32_16x16x32_bf16(a.s, b.s, acc, 0, 0, 0);
  }
  __syncthreads();   // S4

  // ---- P half 1 (m = 16..31) ----
#pragma unroll
  for (int jj = 0; jj < 4; jj++) {
    int mloc = w * 4 + jj;
    float hm = h2a[16 + mloc];
    uint4 d0, d1;
    d0.x = pk2(hm*xs[0],  hm*xs[1]);  d0.y = pk2(hm*xs[2],  hm*xs[3]);
    d0.z = pk2(hm*xs[4],  hm*xs[5]);  d0.w = pk2(hm*xs[6],  hm*xs[7]);
    d1.x = pk2(hm*xs[8],  hm*xs[9]);  d1.y = pk2(hm*xs[10], hm*xs[11]);
    d1.z = pk2(hm*xs[12], hm*xs[13]); d1.w = pk2(hm*xs[14], hm*xs[15]);
    uint4* row = (uint4*)&P[l * 148 + mloc * 8];
    row[0] = d0; row[1] = d1;
  }
  __syncthreads();   // S5

#pragma unroll
  for (int t = 0; t < 8; t++) {
    FragU a, b;
    a.u = *(const uint4*)(Arow + t * 16 + q4);
    b.u = WF[(8 + t) * 64 + l];
    acc = __builtin_amdgcn_mfma_f32_16x16x32_bf16(a.s, b.s, acc, 0, 0, 0);
  }

  // ---- kv epilogue: scale in-reg, stage in h2S region (stride 20), coalesced store ----
  {
    float* kvS = h2S;  // dead since S3; different region than P (no race with MFMA reads)
#pragma unroll
    for (int r = 0; r < 4; r++) {
      int eloc = w * 16 + quad * 4 + r;
      float bsc = F_Y0 * scaleP[eb + eloc];
      kvS[eloc * 20 + lo] = acc[r] * bsc;
    }
  }
  __syncthreads();   // S6: staging complete
  {
    int e = tid >> 2, c = tid & 3;
    float4 v = *(const float4*)&h2S[e * 20 + c * 4];
    ((float4*)(kvE + (size_t)eb * 16))[tid] = v;
  }
}

// ---------------- fused softmax + aggregation gather (kvE layout) ----------------
__global__ __launch_bounds__(256) void k_gather_agg(
    const int* __restrict__ row_ptr, const float* __restrict__ scaleP,
    const float* __restrict__ kvE, const float* __restrict__ q,
    float* __restrict__ agg, int N, int E)
{
  int t = blockIdx.x * 256 + threadIdx.x;
  if (t >= N * 8) return;
  int n = t >> 3;
  int h = t & 7;
  float qh = q[t];
  int j0 = row_ptr[n], j1 = row_ptr[n + 1];
  float num = 0.f, den = 0.f;
  for (int j = j0; j < j1; ++j) {
    float key = kvE[(size_t)j * 16 + 8 + h];
    float val = kvE[(size_t)j * 16 + h];
    float lg = fminf(key * qh, 60.0f);
    float w = scaleP[j] * __expf(lg);
    num += w * val;
    den += w;
  }
  agg[t] = num / fmaxf(den, 1e-20f);
}

// ---------------- feats gather (kvE layout) ----------------
__global__ __launch_bounds__(256) void k_gather_feats(
    const int* __restrict__ row_ptr, const float* __restrict__ kvE,
    float* __restrict__ feats, int N, int E)
{
  int t = blockIdx.x * 256 + threadIdx.x;
  if (t >= N * 16) return;
  int n = t >> 4;
  int o = t & 15;
  int j0 = row_ptr[n], j1 = row_ptr[n + 1];
  float a = 0.f;
  for (int j = j0; j < j1; ++j) a += kvE[(size_t)j * 16 + o];
  feats[t] = a;
}

// ---------------- node update ----------------
__global__ __launch_bounds__(256) void k_node_update(
    const float* __restrict__ agg, const float* __restrict__ xin,
    const float* __restrict__ Wproj, const float* __restrict__ Wq_next,
    float* __restrict__ xout, float* __restrict__ q, int N)
{
  int n = blockIdx.x * 256 + threadIdx.x;
  if (n >= N) return;
  float cat[24];
  load8(agg + (size_t)n * 8, cat);
  load16(xin + (size_t)n * 16, cat + 8);
  float xn[16];
#pragma unroll
  for (int o = 0; o < 16; o++) {
    float a = 0.f;
#pragma unroll
    for (int j = 0; j < 24; j++) a += Wproj[o * 24 + j] * cat[j];
    xn[o] = a;
  }
  store16(xout + (size_t)n * 16, xn);
  float qv[8];
#pragma unroll
  for (int h = 0; h < 8; h++) {
    float a = 0.f;
#pragma unroll
    for (int i = 0; i < 16; i++) a += Wq_next[h * 16 + i] * xn[i];
    qv[h] = a;
  }
  store8(q + (size_t)n * 8, qv);
}

// ---------------- final node MLP -> per-block partials ----------------
__global__ __launch_bounds__(256) void k_node_final(
    const float* __restrict__ x, const float* __restrict__ semb,
    const float* __restrict__ feats, const float* __restrict__ Wself,
    const float* __restrict__ mW1, const float* __restrict__ mb1,
    const float* __restrict__ mW2, const float* __restrict__ mb2,
    const float* __restrict__ mW3, const float* __restrict__ mb3,
    float* __restrict__ learn_part, int N)
{
  int n = blockIdx.x * 256 + threadIdx.x;
  float learned = 0.f;
  if (n < N) {
    float xv[16], ft[16], sb[16];
    load16(x + (size_t)n * 16, xv);
    load16(feats + (size_t)n * 16, ft);
    load16(semb + (size_t)n * 16, sb);
    float cat[32];
#pragma unroll
    for (int i = 0; i < 16; i++) cat[i] = sb[i];
#pragma unroll
    for (int o = 0; o < 16; o++) {
      float a = ft[o];
#pragma unroll
      for (int i = 0; i < 16; i++) a += Wself[o * 16 + i] * xv[i];
      cat[16 + o] = a;
    }
    float hh[16];
#pragma unroll
    for (int j = 0; j < 16; j++) {
      float a = mb1[j];
#pragma unroll
      for (int k = 0; k < 32; k++) a += cat[k] * mW1[k * 16 + j];
      hh[j] = siluf(a);
    }
    float h2[16];
#pragma unroll
    for (int j = 0; j < 16; j++) {
      float a = mb2[j];
#pragma unroll
      for (int k = 0; k < 16; k++) a += hh[k] * mW2[k * 16 + j];
      h2[j] = siluf(a);
    }
    float a = mb3[0];
#pragma unroll
    for (int k = 0; k < 16; k++) a += h2[k] * mW3[k];
    learned = a;
  }
  block_reduce_store(learned, learn_part);
}

// ---------------- final reduction ----------------
__global__ __launch_bounds__(256) void k_finalize(
    const float* __restrict__ coul_part, int nc,
    const float* __restrict__ learn_part, int nl,
    float* __restrict__ out)
{
  __shared__ float sred[4];
  int tid = threadIdx.x;
  float v = 0.f;
  for (int i = tid; i < nc; i += 256) v += coul_part[i];
  for (int i = tid; i < nl; i += 256) v += learn_part[i];
#pragma unroll
  for (int off = 32; off > 0; off >>= 1) v += __shfl_down(v, off, 64);
  if ((tid & 63) == 0) sred[tid >> 6] = v;
  __syncthreads();
  if (tid == 0) out[0] = sred[0] + sred[1] + sred[2] + sred[3];
}

extern "C" void kernel_launch(void* const* d_in, const int* in_sizes, int n_in,
                              void* d_out, int out_size, void* d_ws, size_t ws_size,
                              hipStream_t stream)
{
  const int*   species = (const int*)d_in[0];
  const int*   src     = (const int*)d_in[1];
  const int*   dst     = (const int*)d_in[2];
  const float* rel_pos = (const float*)d_in[3];
  const float* emb     = (const float*)d_in[4];
  const float* kv_W1   = (const float*)d_in[5];
  const float* kv_b1   = (const float*)d_in[6];
  const float* kv_W2   = (const float*)d_in[7];
  const float* kv_b2   = (const float*)d_in[8];
  const float* kv_W3   = (const float*)d_in[9];
  const float* kv_b3   = (const float*)d_in[10];
  const float* Wq      = (const float*)d_in[11];
  const float* Wproj   = (const float*)d_in[12];
  const float* fin_W1  = (const float*)d_in[13];
  const float* fin_b1  = (const float*)d_in[14];
  const float* fin_W2  = (const float*)d_in[15];
  const float* fin_b2  = (const float*)d_in[16];
  const float* fin_W3  = (const float*)d_in[17];
  const float* fin_b3  = (const float*)d_in[18];
  const float* Wself   = (const float*)d_in[19];
  const float* mlp_W1  = (const float*)d_in[20];
  const float* mlp_b1  = (const float*)d_in[21];
  const float* mlp_W2  = (const float*)d_in[22];
  const float* mlp_b2  = (const float*)d_in[23];
  const float* mlp_W3  = (const float*)d_in[24];
  const float* mlp_b3  = (const float*)d_in[25];

  const int N = in_sizes[0];
  const int E = in_sizes[1];
  const int nblk_e = (E + 255) / 256;
  const int nblk_n = (N + 255) / 256;

  char* p = (char*)d_ws;
  auto alloc = [&](size_t bytes) -> void* {
    void* r = (void*)p;
    p += (bytes + 255) & ~(size_t)255;
    return r;
  };
  float* dist_   = (float*)alloc((size_t)E * 4);
  float* scale_  = (float*)alloc((size_t)E * 4);
  float* distP   = (float*)alloc((size_t)E * 4);
  float* scaleP  = (float*)alloc((size_t)E * 4);
  int*   srcP    = (int*)  alloc((size_t)E * 4);
  float* ef      = (float*)alloc((size_t)E * 16 * 4);
  float* kvE     = (float*)alloc((size_t)E * 16 * 4);
  float* xA      = (float*)alloc((size_t)N * 16 * 4);
  float* xB      = (float*)alloc((size_t)N * 16 * 4);
  float* q       = (float*)alloc((size_t)N * 8 * 4);
  float* semb    = (float*)alloc((size_t)N * 16 * 4);
  float* agg     = (float*)alloc((size_t)N * 8 * 4);
  float* feats   = (float*)alloc((size_t)N * 16 * 4);
  int*   cnt     = (int*)  alloc((size_t)N * 4);
  int*   row_ptr = (int*)  alloc((size_t)(N + 1) * 4);
  int*   row_cur = (int*)  alloc((size_t)N * 4);
  int*   bsum    = (int*)  alloc(128 * 4);
  int*   boff    = (int*)  alloc(128 * 4);
  uint4* WF      = (uint4*)alloc((size_t)5 * 19 * 64 * 16);
  float* coul_part  = (float*)alloc((size_t)nblk_e * 4);
  float* learn_part = (float*)alloc((size_t)nblk_n * 4);

  dim3 blk(256);
  dim3 egrid(nblk_e);
  dim3 cgrid(E / 64);
  dim3 ngrid(nblk_n);
  dim3 n8grid((N * 8 + 255) / 256);
  dim3 n16grid((N * 16 + 255) / 256);

  hipMemsetAsync(cnt, 0, (size_t)N * 4, stream);

  k_prepack<<<dim3(24), blk, 0, stream>>>(kv_W3, kv_b3, fin_W3, fin_b3,
                                          kv_W2, fin_W2, WF);

  k_pre<<<egrid, blk, 0, stream>>>(species, src, dst, rel_pos, dist_, scale_,
                                   coul_part, E);
  k_hist<<<egrid, blk, 0, stream>>>(dst, cnt, E);
  k_scan1<<<ngrid, blk, 0, stream>>>(cnt, row_ptr, bsum);
  k_scan2<<<dim3(1), dim3(128), 0, stream>>>(bsum, boff);
  k_scan3<<<ngrid, blk, 0, stream>>>(row_ptr, row_cur, boff, N, E);
  k_scatter<<<egrid, blk, 0, stream>>>(src, dst, dist_, scale_, row_cur,
                                       srcP, distP, scaleP, E);

  k_node_init<<<ngrid, blk, 0, stream>>>(species, emb, Wq, xA, semb, q, N);

  float* xin = xA;
  float* xout = xB;
  for (int l = 0; l < 4; l++) {
    const float* W1 = kv_W1 + (size_t)l * 16 * 32;
    const float* B1 = kv_b1 + (size_t)l * 32;
    const float* B2 = kv_b2 + (size_t)l * 32;
    const uint4* WFl = WF + (size_t)l * 19 * 64;
    const float* Wqn = Wq + (size_t)((l < 3) ? (l + 1) : 0) * 8 * 16;
    if (l == 0) {
      k_edge_conv<0><<<cgrid, blk, 0, stream>>>(srcP, scaleP, distP, ef, xin,
                                                W1, B1, B2, WFl, kvE, E);
    } else if (l == 1) {
      k_edge_conv<1><<<cgrid, blk, 0, stream>>>(srcP, scaleP, distP, ef, xin,
                                                W1, B1, B2, WFl, kvE, E);
    } else {
      k_edge_conv<2><<<cgrid, blk, 0, stream>>>(srcP, scaleP, distP, ef, xin,
                                                W1, B1, B2, WFl, kvE, E);
    }
    k_gather_agg<<<n8grid, blk, 0, stream>>>(row_ptr, scaleP, kvE, q, agg, N, E);
    k_node_update<<<ngrid, blk, 0, stream>>>(agg, xin, Wproj + (size_t)l * 16 * 24, Wqn,
                                             xout, q, N);
    float* tmp = xin; xin = xout; xout = tmp;
  }

  k_edge_conv<3><<<cgrid, blk, 0, stream>>>(srcP, scaleP, distP, ef, xin,
                                            fin_W1, fin_b1, fin_b2,
                                            WF + (size_t)4 * 19 * 64, kvE, E);
  k_gather_feats<<<n16grid, blk, 0, stream>>>(row_ptr, kvE, feats, N, E);
  k_node_final<<<ngrid, blk, 0, stream>>>(xin, semb, feats, Wself,
                                          mlp_W1, mlp_b1, mlp_W2, mlp_b2, mlp_W3, mlp_b3,
                                          learn_part, N);
  k_finalize<<<dim3(1), blk, 0, stream>>>(coul_part, nblk_e, learn_part, nblk_n,
                                          (float*)d_out);
}

// Round 9
// 611.368 us; speedup vs baseline: 1.3708x; 1.3708x over previous
//
#include <hip/hip_runtime.h>

constexpr float F_Y0     = 0.28209479177387814f;
constexpr float F_CUTOFF = 4.6f;

typedef short short8 __attribute__((ext_vector_type(8)));
typedef float f32x4  __attribute__((ext_vector_type(4)));

__device__ __forceinline__ float siluf(float v) { return v / (1.0f + __expf(-v)); }

// gfx950 hardware packed fp32->bf16 (RNE): lo = cvt(a), hi = cvt(b)
__device__ __forceinline__ unsigned pk2(float a, float b) {
  unsigned r;
  asm("v_cvt_pk_bf16_f32 %0, %1, %2" : "=v"(r) : "v"(a), "v"(b));
  return r;
}

union FragU { uint4 u; short8 s; };

__device__ __forceinline__ void load16(const float* p, float* r) {
  const float4* p4 = (const float4*)p;
#pragma unroll
  for (int i = 0; i < 4; i++) {
    float4 t = p4[i];
    r[4*i] = t.x; r[4*i+1] = t.y; r[4*i+2] = t.z; r[4*i+3] = t.w;
  }
}
__device__ __forceinline__ void store16(float* p, const float* r) {
  float4* p4 = (float4*)p;
#pragma unroll
  for (int i = 0; i < 4; i++) p4[i] = make_float4(r[4*i], r[4*i+1], r[4*i+2], r[4*i+3]);
}
__device__ __forceinline__ void load8(const float* p, float* r) {
  const float4* p4 = (const float4*)p;
#pragma unroll
  for (int i = 0; i < 2; i++) {
    float4 t = p4[i];
    r[4*i] = t.x; r[4*i+1] = t.y; r[4*i+2] = t.z; r[4*i+3] = t.w;
  }
}
__device__ __forceinline__ void store8(float* p, const float* r) {
  float4* p4 = (float4*)p;
#pragma unroll
  for (int i = 0; i < 2; i++) p4[i] = make_float4(r[4*i], r[4*i+1], r[4*i+2], r[4*i+3]);
}

// block-level sum of one float per thread -> part[blockIdx.x]
__device__ __forceinline__ void block_reduce_store(float v, float* part) {
  __shared__ float sred[4];
  int tid = threadIdx.x;
#pragma unroll
  for (int off = 32; off > 0; off >>= 1) v += __shfl_down(v, off, 64);
  if ((tid & 63) == 0) sred[tid >> 6] = v;
  __syncthreads();
  if (tid == 0) part[blockIdx.x] = sred[0] + sred[1] + sred[2] + sred[3];
}

// ---------------- per-edge precompute (+ CSR histogram fused) ----------------
__global__ __launch_bounds__(256) void k_pre(
    const int* __restrict__ species, const int* __restrict__ src, const int* __restrict__ dst,
    const float* __restrict__ rel_pos,
    float* __restrict__ dist_, float* __restrict__ scale_,
    int* __restrict__ cnt,
    float* __restrict__ coul_part, int E)
{
  int e = blockIdx.x * 256 + threadIdx.x;
  float ce = 0.0f;
  if (e < E) {
    float px = rel_pos[3*(size_t)e + 0];
    float py = rel_pos[3*(size_t)e + 1];
    float pz = rel_pos[3*(size_t)e + 2];
    float dist = sqrtf(px*px + py*py + pz*pz);
    float xc = dist * (1.0f / F_CUTOFF);
    bool in_cut = dist < F_CUTOFF;
    float x2 = in_cut ? xc * xc : 0.0f;
    x2 = fminf(x2, 1.0f - 1e-6f);
    float sc = in_cut ? __expf(3.0f - 3.0f / (1.0f - x2)) : 0.0f;
    dist_[e] = dist;
    scale_[e] = sc;
    atomicAdd(&cnt[dst[e]], 1);
    float Zu = (float)species[src[e]];
    float Zv = (float)species[dst[e]];
    float raw = 0.529f * Zu * Zv / (2.0f * dist);
    float au = 0.8854f * 0.529f / (__powf(Zu, 0.23f) + __powf(Zv, 0.23f));
    float xx = dist / au;
    float screen = 0.1818f   * __expf(-3.2f    * xx)
                 + 0.5099f   * __expf(-0.9423f * xx)
                 + 0.2802f   * __expf(-0.4028f * xx)
                 + 0.02817f  * __expf(-0.2016f * xx);
    ce = raw * screen * sc;
  }
  block_reduce_store(ce, coul_part);
}

// ---------------- CSR scans ----------------
__global__ __launch_bounds__(256) void k_scan1(
    const int* __restrict__ cnt, int* __restrict__ row_ptr, int* __restrict__ bsum)
{
  __shared__ int s[256];
  int tid = threadIdx.x;
  int n = blockIdx.x * 256 + tid;
  int v = cnt[n];
  s[tid] = v;
  __syncthreads();
#pragma unroll
  for (int off = 1; off < 256; off <<= 1) {
    int t = (tid >= off) ? s[tid - off] : 0;
    __syncthreads();
    s[tid] += t;
    __syncthreads();
  }
  row_ptr[n] = s[tid] - v;
  if (tid == 255) bsum[blockIdx.x] = s[255];
}

__global__ __launch_bounds__(128) void k_scan2(int* __restrict__ bsum, int* __restrict__ boff)
{
  __shared__ int s[128];
  int tid = threadIdx.x;
  int v = bsum[tid];
  s[tid] = v;
  __syncthreads();
#pragma unroll
  for (int off = 1; off < 128; off <<= 1) {
    int t = (tid >= off) ? s[tid - off] : 0;
    __syncthreads();
    s[tid] += t;
    __syncthreads();
  }
  boff[tid] = s[tid] - v;
}

__global__ __launch_bounds__(256) void k_scan3(
    int* __restrict__ row_ptr, int* __restrict__ row_cur,
    const int* __restrict__ boff, int N, int E)
{
  int n = blockIdx.x * 256 + threadIdx.x;
  int rp = row_ptr[n] + boff[blockIdx.x];
  row_ptr[n] = rp;
  row_cur[n] = rp;
  if (n == 0) row_ptr[N] = E;
}

// scatter only the permutation index (1 random 4B write/edge)
__global__ __launch_bounds__(256) void k_scatter_perm(
    const int* __restrict__ dst, int* __restrict__ row_cur,
    int* __restrict__ perm, int E)
{
  int e = blockIdx.x * 256 + threadIdx.x;
  if (e >= E) return;
  int pos = atomicAdd(&row_cur[dst[e]], 1);
  perm[pos] = e;
}

// gather payloads into dst-sorted order (coalesced writes; reads L2-resident)
__global__ __launch_bounds__(256) void k_permute(
    const int* __restrict__ perm,
    const int* __restrict__ src, const float* __restrict__ dist_, const float* __restrict__ scale_,
    int* __restrict__ srcP, float* __restrict__ distP, float* __restrict__ scaleP, int E)
{
  int i = blockIdx.x * 256 + threadIdx.x;
  if (i >= E) return;
  int e = perm[i];
  srcP[i]   = src[e];
  distP[i]  = dist_[e];
  scaleP[i] = scale_[e];
}

// ---------------- weight prepack: per layer 19 bf16 B-fragments ----------------
__global__ __launch_bounds__(256) void k_prepack(
    const float* __restrict__ kv_W3, const float* __restrict__ kv_b3,
    const float* __restrict__ fin_W3, const float* __restrict__ fin_b3,
    const float* __restrict__ kv_W2, const float* __restrict__ fin_W2,
    uint4* __restrict__ WF)
{
  int t = blockIdx.x * 256 + threadIdx.x;
  if (t >= 5 * 19 * 64) return;
  int lyr = t / (19 * 64);
  int rem = t - lyr * 19 * 64;
  int f = rem >> 6;
  int l = rem & 63;
  int qq = l >> 4;
  int o = l & 15;
  const float* W3 = (lyr < 4) ? (kv_W3 + (size_t)lyr * 32 * 256) : fin_W3;
  const float* B3 = (lyr < 4) ? (kv_b3 + (size_t)lyr * 256) : fin_b3;
  const float* W2 = (lyr < 4) ? (kv_W2 + (size_t)lyr * 32 * 32) : fin_W2;
  float v[8];
#pragma unroll
  for (int j = 0; j < 8; j++) {
    if (f < 16) {
      int kk = f * 32 + qq * 8 + j;
      int m = kk >> 4, i = kk & 15;
      v[j] = W3[m * 256 + o * 16 + i];
    } else if (f == 16) {
      int r = qq * 8 + j;
      int mp = r >> 4, i = r & 15;
      v[j] = mp ? 0.0f : B3[o * 16 + i];
    } else {
      int c = f - 17;
      int k = qq * 8 + j;
      v[j] = W2[k * 32 + c * 16 + o];
    }
  }
  uint4 dw;
  dw.x = pk2(v[0], v[1]);
  dw.y = pk2(v[2], v[3]);
  dw.z = pk2(v[4], v[5]);
  dw.w = pk2(v[6], v[7]);
  WF[t] = dw;
}

// ---------------- node init ----------------
__global__ __launch_bounds__(256) void k_node_init(
    const int* __restrict__ species, const float* __restrict__ emb,
    const float* __restrict__ Wq0,
    float* __restrict__ x, float* __restrict__ semb, float* __restrict__ q, int N)
{
  int n = blockIdx.x * 256 + threadIdx.x;
  if (n >= N) return;
  int sp = species[n] - 1;
  float xv[16];
  load16(emb + (size_t)sp * 16, xv);
  store16(x + (size_t)n * 16, xv);
  store16(semb + (size_t)n * 16, xv);
  float qv[8];
#pragma unroll
  for (int h = 0; h < 8; h++) {
    float a = 0.f;
#pragma unroll
    for (int i = 0; i < 16; i++) a += Wq0[h * 16 + i] * xv[i];
    qv[h] = a;
  }
  store8(q + (size_t)n * 8, qv);
}

// ---------------- heavy edge conv (MFMA for h2 and W3) ----------------
// ef is never materialized: ef_l[e] = dist-init[e] + xsum_l[src[e]] where
// xsum accumulates node updates (maintained in k_node_update).
// MODE 0: layer 0 (h1 from dist only). MODE 1: ef = xs + dist-init.
// MODE 2: ef = xsum[src] + dist-init (layers 2,3 and final conv).
template <int MODE>
__global__ __launch_bounds__(256, 3) void k_edge_conv(
    const int* __restrict__ srcP,
    const float* __restrict__ scaleP, const float* __restrict__ distP,
    const float* __restrict__ xsum, const float* __restrict__ x,
    const float* __restrict__ W1, const float* __restrict__ B1,
    const float* __restrict__ B2,
    const uint4* __restrict__ WF,
    float* __restrict__ kvE, int E)
{
  __shared__ unsigned P[64 * 148];    // 37888 B
  __shared__ unsigned h1P[64 * 20];   //  5120 B  bf16 h1 [edge][16 dw + pad]
  __shared__ float    h2S[64 * 36];   //  9216 B  fp32 h2; reused as kv staging

  int tid = threadIdx.x;
  int w = __builtin_amdgcn_readfirstlane(tid >> 6);
  int l = tid & 63;
  int quad = l >> 4;
  int lo = l & 15;
  int q4 = quad * 4;
  int eb = blockIdx.x * 64;
  int el = eb + l;

  int s = srcP[el];
  float xs[16];
  load16(x + (size_t)s * 16, xs);

  // ---- h1 (wave w: m = w*8 .. w*8+7) ----
  float h1v[8];
  if (MODE == 0) {
    float dd = distP[el];
#pragma unroll
    for (int jj = 0; jj < 8; jj++) {
      int m = w * 8 + jj;
      h1v[jj] = fmaxf(B1[m] + dd * W1[15 * 32 + m], 0.f);
    }
  } else {
    float efv[16];
    if (MODE == 1) {
#pragma unroll
      for (int i = 0; i < 16; i++) efv[i] = xs[i];
    } else {
      load16(xsum + (size_t)s * 16, efv);
    }
    efv[15] += distP[el];
#pragma unroll
    for (int jj = 0; jj < 8; jj++) {
      int m = w * 8 + jj;
      float a = B1[m];
#pragma unroll
      for (int i = 0; i < 16; i++) a += efv[i] * W1[i * 32 + m];
      h1v[jj] = fmaxf(a, 0.f);
    }
  }
  {
    uint4 hq;
    hq.x = pk2(h1v[0], h1v[1]);
    hq.y = pk2(h1v[2], h1v[3]);
    hq.z = pk2(h1v[4], h1v[5]);
    hq.w = pk2(h1v[6], h1v[7]);
    *(uint4*)&h1P[l * 20 + w * 4] = hq;
  }
  __syncthreads();   // S1: h1P ready

  // ---- h2 via MFMA ----
  {
    FragU a, b0, b1;
    a.u = *(const uint4*)&h1P[(w * 16 + lo) * 20 + q4];
    b0.u = WF[17 * 64 + l];
    b1.u = WF[18 * 64 + l];
    f32x4 hc0 = {0.f, 0.f, 0.f, 0.f};
    f32x4 hc1 = {0.f, 0.f, 0.f, 0.f};
    hc0 = __builtin_amdgcn_mfma_f32_16x16x32_bf16(a.s, b0.s, hc0, 0, 0, 0);
    hc1 = __builtin_amdgcn_mfma_f32_16x16x32_bf16(a.s, b1.s, hc1, 0, 0, 0);
    float b2a = B2[lo];
    float b2b = B2[16 + lo];
#pragma unroll
    for (int r = 0; r < 4; r++) {
      int e = quad * 4 + r;
      h2S[(w * 16 + e) * 36 + lo]      = fmaxf(hc0[r] + b2a, 0.f);
      h2S[(w * 16 + e) * 36 + 16 + lo] = fmaxf(hc1[r] + b2b, 0.f);
    }
  }
  __syncthreads();   // S2: h2S ready

  // ---- own-edge h2 (fp32) ----
  float h2a[32];
  {
    const float4* hp = (const float4*)&h2S[l * 36];
#pragma unroll
    for (int c = 0; c < 8; c++) {
      float4 t = hp[c];
      h2a[4*c] = t.x; h2a[4*c+1] = t.y; h2a[4*c+2] = t.z; h2a[4*c+3] = t.w;
    }
  }

  // ---- P half 0 (m = 0..15) + bias rows ----
#pragma unroll
  for (int jj = 0; jj < 4; jj++) {
    int mloc = w * 4 + jj;
    float hm = h2a[mloc];
    uint4 d0, d1;
    d0.x = pk2(hm*xs[0],  hm*xs[1]);  d0.y = pk2(hm*xs[2],  hm*xs[3]);
    d0.z = pk2(hm*xs[4],  hm*xs[5]);  d0.w = pk2(hm*xs[6],  hm*xs[7]);
    d1.x = pk2(hm*xs[8],  hm*xs[9]);  d1.y = pk2(hm*xs[10], hm*xs[11]);
    d1.z = pk2(hm*xs[12], hm*xs[13]); d1.w = pk2(hm*xs[14], hm*xs[15]);
    uint4* row = (uint4*)&P[l * 148 + mloc * 8];
    row[0] = d0; row[1] = d1;
  }
  if (w == 0) {
    uint4 d0, d1;
    d0.x = pk2(xs[0],  xs[1]);  d0.y = pk2(xs[2],  xs[3]);
    d0.z = pk2(xs[4],  xs[5]);  d0.w = pk2(xs[6],  xs[7]);
    d1.x = pk2(xs[8],  xs[9]);  d1.y = pk2(xs[10], xs[11]);
    d1.z = pk2(xs[12], xs[13]); d1.w = pk2(xs[14], xs[15]);
    uint4* row = (uint4*)&P[l * 148 + 128];
    row[0] = d0; row[1] = d1;
  }
  if (w == 1) {
    uint4 z = make_uint4(0, 0, 0, 0);
    uint4* row = (uint4*)&P[l * 148 + 136];
    row[0] = z; row[1] = z;
  }
  __syncthreads();   // S3 (h2S dead after this point)

  f32x4 acc = {0.f, 0.f, 0.f, 0.f};
  const unsigned* Arow = &P[(w * 16 + lo) * 148];
#pragma unroll
  for (int t = 0; t < 8; t++) {
    FragU a, b;
    a.u = *(const uint4*)(Arow + t * 16 + q4);
    b.u = WF[t * 64 + l];
    acc = __builtin_amdgcn_mfma_f32_16x16x32_bf16(a.s, b.s, acc, 0, 0, 0);
  }
  {
    FragU a, b;
    a.u = *(const uint4*)(Arow + 128 + q4);
    b.u = WF[16 * 64 + l];
    acc = __builtin_amdgcn_mfma_f32_16x16x32_bf16(a.s, b.s, acc, 0, 0, 0);
  }
  __syncthreads();   // S4

  // ---- P half 1 (m = 16..31) ----
#pragma unroll
  for (int jj = 0; jj < 4; jj++) {
    int mloc = w * 4 + jj;
    float hm = h2a[16 + mloc];
    uint4 d0, d1;
    d0.x = pk2(hm*xs[0],  hm*xs[1]);  d0.y = pk2(hm*xs[2],  hm*xs[3]);
    d0.z = pk2(hm*xs[4],  hm*xs[5]);  d0.w = pk2(hm*xs[6],  hm*xs[7]);
    d1.x = pk2(hm*xs[8],  hm*xs[9]);  d1.y = pk2(hm*xs[10], hm*xs[11]);
    d1.z = pk2(hm*xs[12], hm*xs[13]); d1.w = pk2(hm*xs[14], hm*xs[15]);
    uint4* row = (uint4*)&P[l * 148 + mloc * 8];
    row[0] = d0; row[1] = d1;
  }
  __syncthreads();   // S5

#pragma unroll
  for (int t = 0; t < 8; t++) {
    FragU a, b;
    a.u = *(const uint4*)(Arow + t * 16 + q4);
    b.u = WF[(8 + t) * 64 + l];
    acc = __builtin_amdgcn_mfma_f32_16x16x32_bf16(a.s, b.s, acc, 0, 0, 0);
  }

  // ---- kv epilogue: scale in-reg, stage in h2S (stride 20), coalesced store ----
  {
    float* kvS = h2S;  // dead since S3
#pragma unroll
    for (int r = 0; r < 4; r++) {
      int eloc = w * 16 + quad * 4 + r;
      float bsc = F_Y0 * scaleP[eb + eloc];
      kvS[eloc * 20 + lo] = acc[r] * bsc;
    }
  }
  __syncthreads();   // S6
  {
    int e = tid >> 2, c = tid & 3;
    float4 v = *(const float4*)&h2S[e * 20 + c * 4];
    ((float4*)(kvE + (size_t)eb * 16))[tid] = v;
  }
}

// ---------------- fused softmax + aggregation gather (kvE layout) ----------------
__global__ __launch_bounds__(256) void k_gather_agg(
    const int* __restrict__ row_ptr, const float* __restrict__ scaleP,
    const float* __restrict__ kvE, const float* __restrict__ q,
    float* __restrict__ agg, int N, int E)
{
  int t = blockIdx.x * 256 + threadIdx.x;
  if (t >= N * 8) return;
  int n = t >> 3;
  int h = t & 7;
  float qh = q[t];
  int j0 = row_ptr[n], j1 = row_ptr[n + 1];
  float num = 0.f, den = 0.f;
  for (int j = j0; j < j1; ++j) {
    float key = kvE[(size_t)j * 16 + 8 + h];
    float val = kvE[(size_t)j * 16 + h];
    float lg = fminf(key * qh, 60.0f);
    float w = scaleP[j] * __expf(lg);
    num += w * val;
    den += w;
  }
  agg[t] = num / fmaxf(den, 1e-20f);
}

// ---------------- feats gather (kvE layout) ----------------
__global__ __launch_bounds__(256) void k_gather_feats(
    const int* __restrict__ row_ptr, const float* __restrict__ kvE,
    float* __restrict__ feats, int N, int E)
{
  int t = blockIdx.x * 256 + threadIdx.x;
  if (t >= N * 16) return;
  int n = t >> 4;
  int o = t & 15;
  int j0 = row_ptr[n], j1 = row_ptr[n + 1];
  float a = 0.f;
  for (int j = j0; j < j1; ++j) a += kvE[(size_t)j * 16 + o];
  feats[t] = a;
}

// ---------------- node update (maintains xsum for ef reconstruction) ----------------
template <bool INIT>
__global__ __launch_bounds__(256) void k_node_update(
    const float* __restrict__ agg, const float* __restrict__ xin,
    const float* __restrict__ Wproj, const float* __restrict__ Wq_next,
    float* __restrict__ xout, float* __restrict__ q, float* __restrict__ xsum, int N)
{
  int n = blockIdx.x * 256 + threadIdx.x;
  if (n >= N) return;
  float cat[24];
  load8(agg + (size_t)n * 8, cat);
  load16(xin + (size_t)n * 16, cat + 8);
  float xn[16];
#pragma unroll
  for (int o = 0; o < 16; o++) {
    float a = 0.f;
#pragma unroll
    for (int j = 0; j < 24; j++) a += Wproj[o * 24 + j] * cat[j];
    xn[o] = a;
  }
  store16(xout + (size_t)n * 16, xn);
  if (INIT) {
    store16(xsum + (size_t)n * 16, xn);
  } else {
    float sv[16];
    load16(xsum + (size_t)n * 16, sv);
#pragma unroll
    for (int i = 0; i < 16; i++) sv[i] += xn[i];
    store16(xsum + (size_t)n * 16, sv);
  }
  float qv[8];
#pragma unroll
  for (int h = 0; h < 8; h++) {
    float a = 0.f;
#pragma unroll
    for (int i = 0; i < 16; i++) a += Wq_next[h * 16 + i] * xn[i];
    qv[h] = a;
  }
  store8(q + (size_t)n * 8, qv);
}

// ---------------- final node MLP -> per-block partials ----------------
__global__ __launch_bounds__(256) void k_node_final(
    const float* __restrict__ x, const float* __restrict__ semb,
    const float* __restrict__ feats, const float* __restrict__ Wself,
    const float* __restrict__ mW1, const float* __restrict__ mb1,
    const float* __restrict__ mW2, const float* __restrict__ mb2,
    const float* __restrict__ mW3, const float* __restrict__ mb3,
    float* __restrict__ learn_part, int N)
{
  int n = blockIdx.x * 256 + threadIdx.x;
  float learned = 0.f;
  if (n < N) {
    float xv[16], ft[16], sb[16];
    load16(x + (size_t)n * 16, xv);
    load16(feats + (size_t)n * 16, ft);
    load16(semb + (size_t)n * 16, sb);
    float cat[32];
#pragma unroll
    for (int i = 0; i < 16; i++) cat[i] = sb[i];
#pragma unroll
    for (int o = 0; o < 16; o++) {
      float a = ft[o];
#pragma unroll
      for (int i = 0; i < 16; i++) a += Wself[o * 16 + i] * xv[i];
      cat[16 + o] = a;
    }
    float hh[16];
#pragma unroll
    for (int j = 0; j < 16; j++) {
      float a = mb1[j];
#pragma unroll
      for (int k = 0; k < 32; k++) a += cat[k] * mW1[k * 16 + j];
      hh[j] = siluf(a);
    }
    float h2[16];
#pragma unroll
    for (int j = 0; j < 16; j++) {
      float a = mb2[j];
#pragma unroll
      for (int k = 0; k < 16; k++) a += hh[k] * mW2[k * 16 + j];
      h2[j] = siluf(a);
    }
    float a = mb3[0];
#pragma unroll
    for (int k = 0; k < 16; k++) a += h2[k] * mW3[k];
    learned = a;
  }
  block_reduce_store(learned, learn_part);
}

// ---------------- final reduction ----------------
__global__ __launch_bounds__(256) void k_finalize(
    const float* __restrict__ coul_part, int nc,
    const float* __restrict__ learn_part, int nl,
    float* __restrict__ out)
{
  __shared__ float sred[4];
  int tid = threadIdx.x;
  float v = 0.f;
  for (int i = tid; i < nc; i += 256) v += coul_part[i];
  for (int i = tid; i < nl; i += 256) v += learn_part[i];
#pragma unroll
  for (int off = 32; off > 0; off >>= 1) v += __shfl_down(v, off, 64);
  if ((tid & 63) == 0) sred[tid >> 6] = v;
  __syncthreads();
  if (tid == 0) out[0] = sred[0] + sred[1] + sred[2] + sred[3];
}

extern "C" void kernel_launch(void* const* d_in, const int* in_sizes, int n_in,
                              void* d_out, int out_size, void* d_ws, size_t ws_size,
                              hipStream_t stream)
{
  const int*   species = (const int*)d_in[0];
  const int*   src     = (const int*)d_in[1];
  const int*   dst     = (const int*)d_in[2];
  const float* rel_pos = (const float*)d_in[3];
  const float* emb     = (const float*)d_in[4];
  const float* kv_W1   = (const float*)d_in[5];
  const float* kv_b1   = (const float*)d_in[6];
  const float* kv_W2   = (const float*)d_in[7];
  const float* kv_b2   = (const float*)d_in[8];
  const float* kv_W3   = (const float*)d_in[9];
  const float* kv_b3   = (const float*)d_in[10];
  const float* Wq      = (const float*)d_in[11];
  const float* Wproj   = (const float*)d_in[12];
  const float* fin_W1  = (const float*)d_in[13];
  const float* fin_b1  = (const float*)d_in[14];
  const float* fin_W2  = (const float*)d_in[15];
  const float* fin_b2  = (const float*)d_in[16];
  const float* fin_W3  = (const float*)d_in[17];
  const float* fin_b3  = (const float*)d_in[18];
  const float* Wself   = (const float*)d_in[19];
  const float* mlp_W1  = (const float*)d_in[20];
  const float* mlp_b1  = (const float*)d_in[21];
  const float* mlp_W2  = (const float*)d_in[22];
  const float* mlp_b2  = (const float*)d_in[23];
  const float* mlp_W3  = (const float*)d_in[24];
  const float* mlp_b3  = (const float*)d_in[25];

  const int N = in_sizes[0];
  const int E = in_sizes[1];
  const int nblk_e = (E + 255) / 256;
  const int nblk_n = (N + 255) / 256;

  char* p = (char*)d_ws;
  auto alloc = [&](size_t bytes) -> void* {
    void* r = (void*)p;
    p += (bytes + 255) & ~(size_t)255;
    return r;
  };
  float* dist_   = (float*)alloc((size_t)E * 4);
  float* scale_  = (float*)alloc((size_t)E * 4);
  float* distP   = (float*)alloc((size_t)E * 4);
  float* scaleP  = (float*)alloc((size_t)E * 4);
  int*   srcP    = (int*)  alloc((size_t)E * 4);
  int*   perm    = (int*)  alloc((size_t)E * 4);
  float* kvE     = (float*)alloc((size_t)E * 16 * 4);
  float* xA      = (float*)alloc((size_t)N * 16 * 4);
  float* xB      = (float*)alloc((size_t)N * 16 * 4);
  float* xsum    = (float*)alloc((size_t)N * 16 * 4);
  float* q       = (float*)alloc((size_t)N * 8 * 4);
  float* semb    = (float*)alloc((size_t)N * 16 * 4);
  float* agg     = (float*)alloc((size_t)N * 8 * 4);
  float* feats   = (float*)alloc((size_t)N * 16 * 4);
  int*   cnt     = (int*)  alloc((size_t)N * 4);
  int*   row_ptr = (int*)  alloc((size_t)(N + 1) * 4);
  int*   row_cur = (int*)  alloc((size_t)N * 4);
  int*   bsum    = (int*)  alloc(128 * 4);
  int*   boff    = (int*)  alloc(128 * 4);
  uint4* WF      = (uint4*)alloc((size_t)5 * 19 * 64 * 16);
  float* coul_part  = (float*)alloc((size_t)nblk_e * 4);
  float* learn_part = (float*)alloc((size_t)nblk_n * 4);

  dim3 blk(256);
  dim3 egrid(nblk_e);
  dim3 cgrid(E / 64);
  dim3 ngrid(nblk_n);
  dim3 n8grid((N * 8 + 255) / 256);
  dim3 n16grid((N * 16 + 255) / 256);

  hipMemsetAsync(cnt, 0, (size_t)N * 4, stream);

  k_prepack<<<dim3(24), blk, 0, stream>>>(kv_W3, kv_b3, fin_W3, fin_b3,
                                          kv_W2, fin_W2, WF);

  k_pre<<<egrid, blk, 0, stream>>>(species, src, dst, rel_pos, dist_, scale_,
                                   cnt, coul_part, E);
  k_scan1<<<ngrid, blk, 0, stream>>>(cnt, row_ptr, bsum);
  k_scan2<<<dim3(1), dim3(128), 0, stream>>>(bsum, boff);
  k_scan3<<<ngrid, blk, 0, stream>>>(row_ptr, row_cur, boff, N, E);
  k_scatter_perm<<<egrid, blk, 0, stream>>>(dst, row_cur, perm, E);
  k_permute<<<egrid, blk, 0, stream>>>(perm, src, dist_, scale_,
                                       srcP, distP, scaleP, E);

  k_node_init<<<ngrid, blk, 0, stream>>>(species, emb, Wq, xA, semb, q, N);

  float* xin = xA;
  float* xout = xB;
  for (int l = 0; l < 4; l++) {
    const float* W1 = kv_W1 + (size_t)l * 16 * 32;
    const float* B1 = kv_b1 + (size_t)l * 32;
    const float* B2 = kv_b2 + (size_t)l * 32;
    const uint4* WFl = WF + (size_t)l * 19 * 64;
    const float* Wqn = Wq + (size_t)((l < 3) ? (l + 1) : 0) * 8 * 16;
    if (l == 0) {
      k_edge_conv<0><<<cgrid, blk, 0, stream>>>(srcP, scaleP, distP, xsum, xin,
                                                W1, B1, B2, WFl, kvE, E);
    } else if (l == 1) {
      k_edge_conv<1><<<cgrid, blk, 0, stream>>>(srcP, scaleP, distP, xsum, xin,
                                                W1, B1, B2, WFl, kvE, E);
    } else {
      k_edge_conv<2><<<cgrid, blk, 0, stream>>>(srcP, scaleP, distP, xsum, xin,
                                                W1, B1, B2, WFl, kvE, E);
    }
    k_gather_agg<<<n8grid, blk, 0, stream>>>(row_ptr, scaleP, kvE, q, agg, N, E);
    if (l == 0) {
      k_node_update<true><<<ngrid, blk, 0, stream>>>(agg, xin, Wproj, Wq + 8 * 16,
                                                     xout, q, xsum, N);
    } else {
      k_node_update<false><<<ngrid, blk, 0, stream>>>(agg, xin,
                                                      Wproj + (size_t)l * 16 * 24, Wqn,
                                                      xout, q, xsum, N);
    }
    float* tmp = xin; xin = xout; xout = tmp;
  }

  k_edge_conv<2><<<cgrid, blk, 0, stream>>>(srcP, scaleP, distP, xsum, xin,
                                            fin_W1, fin_b1, fin_b2,
                                            WF + (size_t)4 * 19 * 64, kvE, E);
  k_gather_feats<<<n16grid, blk, 0, stream>>>(row_ptr, kvE, feats, N, E);
  k_node_final<<<ngrid, blk, 0, stream>>>(xin, semb, feats, Wself,
                                          mlp_W1, mlp_b1, mlp_W2, mlp_b2, mlp_W3, mlp_b3,
                                          learn_part, N);
  k_finalize<<<dim3(1), blk, 0, stream>>>(coul_part, nblk_e, learn_part, nblk_n,
                                          (float*)d_out);
}